// Round 10
// baseline (350.111 us; speedup 1.0000x reference)
//
#include <hip/hip_runtime.h>

#define M_DIM 4096
#define K_DIM 4096
#define N_DIM 11008
#define PQ (N_DIM / 8)   // 1376 packed columns
#define NTILES 688       // (4096/256) * (11008/256)
#define GRID 256

typedef short short8 __attribute__((ext_vector_type(8)));
typedef float f32x4 __attribute__((ext_vector_type(4)));
typedef __attribute__((address_space(3))) void lds_void;
typedef const __attribute__((address_space(1))) void g_void;

__device__ __forceinline__ unsigned short f2bf(float f) {
  unsigned int u = __float_as_uint(f);
  u += 0x7FFFu + ((u >> 16) & 1u);   // round-to-nearest-even
  return (unsigned short)(u >> 16);
}

// ---- A convert + transpose (coalesced): fp32 [M][K] -> bf16 K-packed Ag[K/8][M][8] ----
__global__ __launch_bounds__(256) void convert_a_t(const float* __restrict__ a,
                                                   unsigned short* __restrict__ ag) {
  __shared__ unsigned short t[8][33][8];   // [m][kb_local][8], padded
  const int tid = threadIdx.x;
  const int mt = blockIdx.x & 511;         // m-tile (m0 = mt*8)
  const int kt = blockIdx.x >> 9;          // k-tile (k0 = kt*256)
  const int m0 = mt * 8;
  const int k0 = kt * 256;
  {
    const int m = tid >> 5, j = tid & 31;
    const float4* src = (const float4*)(a + (size_t)(m0 + m) * K_DIM + k0 + j * 8);
    float4 v0 = src[0];
    float4 v1 = src[1];
    short8 o;
    o[0] = (short)f2bf(v0.x); o[1] = (short)f2bf(v0.y);
    o[2] = (short)f2bf(v0.z); o[3] = (short)f2bf(v0.w);
    o[4] = (short)f2bf(v1.x); o[5] = (short)f2bf(v1.y);
    o[6] = (short)f2bf(v1.z); o[7] = (short)f2bf(v1.w);
    *(short8*)&t[m][j][0] = o;
  }
  __syncthreads();
  {
    const int kb = tid >> 3, mm = tid & 7;
    short8 w = *(const short8*)&t[mm][kb][0];
    *(short8*)(ag + ((size_t)(kt * 32 + kb) * M_DIM + m0 + mm) * 8) = w;
  }
}

// ---- Dequant: qweight [K][P] int32 -> Wg [K/8][N][8] bf16 (K-packed) ----
__global__ __launch_bounds__(256) void dequant_w(const int* __restrict__ qweight,
                                                 const int* __restrict__ qzeros,
                                                 const float* __restrict__ scales,
                                                 unsigned short* __restrict__ wg) {
  int idx = blockIdx.x * 256 + threadIdx.x;
  int n = idx % N_DIM;
  int kb = idx / N_DIM;                 // 0..511
  int g = kb >> 4;
  int p = n >> 3;
  int j = n & 7;
  int sh = ((j >> 1) << 2) | ((j & 1) << 4);   // 4*AWQ_rev[j]
  float zp = (float)((qzeros[g * PQ + p] >> sh) & 0xF);
  float sc = scales[(size_t)g * N_DIM + n];
  short8 o;
#pragma unroll
  for (int e = 0; e < 8; ++e) {
    int q = qweight[(size_t)(kb * 8 + e) * PQ + p];
    float w = ((float)((q >> sh) & 0xF) - zp) * sc;
    o[e] = (short)f2bf(w);
  }
  *(short8*)(wg + ((size_t)kb * N_DIM + n) * 8) = o;
}

// ---------------- 256x256 8-wave pipelined bf16 MFMA GEMM (persistent) ----------------
#define BM 256
#define BN 256
#define BK 64
#define NT (K_DIM / BK)   // 64 K-tiles
// LDS: 2 bufs x (A 16384 + B 16384) shorts = 128 KiB
// buf layout: A [kslot 0..7][row 0..255][8] ; B at +16384 same shape.

__device__ __forceinline__ void stage_half(const unsigned short* __restrict__ g, int ld, int off0,
                                           int krow0, unsigned short* ldsbase, int tid, int wid) {
#pragma unroll
  for (int i = 0; i < 2; ++i) {
    int c = i * 512 + tid;             // chunk id within the 16KB half
    const unsigned short* src = g + ((size_t)(krow0 + (c >> 8)) * ld + off0 + (c & 255)) * 8;
    unsigned short* dst = ldsbase + (i * 512 + wid * 64) * 8;  // wave-uniform; lane adds 16B
    __builtin_amdgcn_global_load_lds((g_void*)src, (lds_void*)dst, 16, 0, 0);
  }
}

__global__ __launch_bounds__(512, 2) void gemm256(const unsigned short* __restrict__ Ag,
                                                  const unsigned short* __restrict__ Wg,
                                                  const float* __restrict__ bias,
                                                  float* __restrict__ C) {
  extern __shared__ __align__(16) unsigned short lds[];   // 65536 shorts = 128 KB
  const int tid = threadIdx.x;
  const int lane = tid & 63;
  const int wid = tid >> 6;      // 0..7
  const int wr = wid >> 2;       // 0..1  (row half: 128 rows)
  const int wc = wid & 3;        // 0..3  (col quarter: 64 cols)

  const int ks = lane >> 4;           // k-slot within half (0..3)
  const int rowA = wr * 128 + (lane & 15);
  const int colB = wc * 64 + (lane & 15);

  // first tile for this block (XCD-bijective swizzle on tile index; 688 % 8 == 0)
  int tile = blockIdx.x;
  int wg0 = (tile & 7) * 86 + (tile >> 3);
  int m0 = (wg0 & 15) * BM;
  int n0 = (wg0 >> 4) * BN;

  f32x4 acc[8][4];
#pragma unroll
  for (int i = 0; i < 8; ++i)
#pragma unroll
    for (int j = 0; j < 4; ++j) acc[i][j] = (f32x4){0.f, 0.f, 0.f, 0.f};

#define A_FRAG(buf, kb, r) (*(const short8*)(lds + (buf) * 32768 + (kb) * 2048 + (r) * 8))
#define B_FRAG(buf, kb, c) (*(const short8*)(lds + (buf) * 32768 + 16384 + (kb) * 2048 + (c) * 8))

  short8 aLo[4], aHi[4], bA[4], bB[4];

  // ---- block prologue: stage tile0 fully; wait; read its s0 frags
  stage_half(Ag, M_DIM, m0, 0, lds + 0, tid, wid);              // A0
  stage_half(Wg, N_DIM, n0, 0, lds + 16384, tid, wid);          // B0
  stage_half(Ag, M_DIM, m0, 4, lds + 8192, tid, wid);           // A1
  stage_half(Wg, N_DIM, n0, 4, lds + 16384 + 8192, tid, wid);   // B1
  asm volatile("s_waitcnt vmcnt(0)" ::: "memory");
  __builtin_amdgcn_s_barrier();
#pragma unroll
  for (int mi = 0; mi < 4; ++mi) aLo[mi] = A_FRAG(0, ks, rowA + mi * 16);
#pragma unroll
  for (int ni = 0; ni < 4; ++ni) bA[ni] = B_FRAG(0, ks, colB + ni * 16);

  while (true) {
    const int nextTile = tile + GRID;
    const bool last = (nextTile >= NTILES);
    const int nI = last ? tile : nextTile;          // dummy-stage own tile at the end
    const int wgn = (nI & 7) * 86 + (nI >> 3);
    const int m0n = (wgn & 15) * BM;
    const int n0n = (wgn >> 4) * BN;

    // ================= main K loop (t = 0 .. NT-2), stages tile-local t+1 =================
    for (int t = 0; t < NT - 1; ++t) {
      const int bs = t & 1;
      const int nb = bs ^ 1;
      unsigned short* nA = lds + nb * 32768;
      unsigned short* nB = nA + 16384;

      // ===== SEG A: issue ALL of tile t+1's staging (8 loads); read aHi(k0); MFMA P1;
      //       counted wait vmcnt(8) drains A1B1(t) while keeping 8 in flight
      stage_half(Ag, M_DIM, m0, (t + 1) * 8, nA, tid, wid);
      stage_half(Wg, N_DIM, n0, (t + 1) * 8, nB, tid, wid);
      stage_half(Ag, M_DIM, m0, (t + 1) * 8 + 4, nA + 8192, tid, wid);
      stage_half(Wg, N_DIM, n0, (t + 1) * 8 + 4, nB + 8192, tid, wid);
#pragma unroll
      for (int mi = 0; mi < 4; ++mi) aHi[mi] = A_FRAG(bs, ks, rowA + 64 + mi * 16);
#pragma unroll
      for (int mi = 0; mi < 4; ++mi)
#pragma unroll
        for (int ni = 0; ni < 4; ++ni)
          acc[mi][ni] = __builtin_amdgcn_mfma_f32_16x16x32_bf16(aLo[mi], bA[ni], acc[mi][ni], 0, 0, 0);
      asm volatile("s_waitcnt vmcnt(8)" ::: "memory");   // A1B1(t) landed; t+1's 8 still flying
      __builtin_amdgcn_s_barrier();

      // ===== SEG B: MFMA P2; read s3 operands; MFMA P3; counted wait vmcnt(4) drains A0B0(t+1)
#pragma unroll
      for (int mi = 0; mi < 4; ++mi) aLo[mi] = A_FRAG(bs, 4 + ks, rowA + mi * 16);
#pragma unroll
      for (int ni = 0; ni < 4; ++ni) bB[ni] = B_FRAG(bs, 4 + ks, colB + ni * 16);
#pragma unroll
      for (int mi = 0; mi < 4; ++mi)
#pragma unroll
        for (int ni = 0; ni < 4; ++ni)
          acc[4 + mi][ni] = __builtin_amdgcn_mfma_f32_16x16x32_bf16(aHi[mi], bA[ni], acc[4 + mi][ni], 0, 0, 0);
#pragma unroll
      for (int mi = 0; mi < 4; ++mi) aHi[mi] = A_FRAG(bs, 4 + ks, rowA + 64 + mi * 16);
#pragma unroll
      for (int mi = 0; mi < 4; ++mi)
#pragma unroll
        for (int ni = 0; ni < 4; ++ni)
          acc[mi][ni] = __builtin_amdgcn_mfma_f32_16x16x32_bf16(aLo[mi], bB[ni], acc[mi][ni], 0, 0, 0);
      asm volatile("s_waitcnt vmcnt(4)" ::: "memory");   // A0B0(t+1) landed; A1B1(t+1) flying
      __builtin_amdgcn_s_barrier();

      // ===== SEG C: read next-iter s0 frags from nb; MFMA P4
#pragma unroll
      for (int mi = 0; mi < 4; ++mi) aLo[mi] = A_FRAG(nb, ks, rowA + mi * 16);
#pragma unroll
      for (int ni = 0; ni < 4; ++ni) bA[ni] = B_FRAG(nb, ks, colB + ni * 16);
#pragma unroll
      for (int mi = 0; mi < 4; ++mi)
#pragma unroll
        for (int ni = 0; ni < 4; ++ni)
          acc[4 + mi][ni] = __builtin_amdgcn_mfma_f32_16x16x32_bf16(aHi[mi], bB[ni], acc[4 + mi][ni], 0, 0, 0);
    }

    // ================= peeled t = NT-1: stages NEXT TILE's halves into buf0 =================
    {
      const int bs = 1, nb = 0;   // (NT-1)&1 = 1
      unsigned short* nA = lds + nb * 32768;
      unsigned short* nB = nA + 16384;

      // SEG A': issue next tile's full staging (8 loads)
      stage_half(Ag, M_DIM, m0n, 0, nA, tid, wid);
      stage_half(Wg, N_DIM, n0n, 0, nB, tid, wid);
      stage_half(Ag, M_DIM, m0n, 4, nA + 8192, tid, wid);
      stage_half(Wg, N_DIM, n0n, 4, nB + 8192, tid, wid);
#pragma unroll
      for (int mi = 0; mi < 4; ++mi) aHi[mi] = A_FRAG(bs, ks, rowA + 64 + mi * 16);
#pragma unroll
      for (int mi = 0; mi < 4; ++mi)
#pragma unroll
        for (int ni = 0; ni < 4; ++ni)
          acc[mi][ni] = __builtin_amdgcn_mfma_f32_16x16x32_bf16(aLo[mi], bA[ni], acc[mi][ni], 0, 0, 0);
      asm volatile("s_waitcnt vmcnt(8)" ::: "memory");   // A1B1(NT-1) landed
      __builtin_amdgcn_s_barrier();

      // SEG B'
#pragma unroll
      for (int mi = 0; mi < 4; ++mi) aLo[mi] = A_FRAG(bs, 4 + ks, rowA + mi * 16);
#pragma unroll
      for (int ni = 0; ni < 4; ++ni) bB[ni] = B_FRAG(bs, 4 + ks, colB + ni * 16);
#pragma unroll
      for (int mi = 0; mi < 4; ++mi)
#pragma unroll
        for (int ni = 0; ni < 4; ++ni)
          acc[4 + mi][ni] = __builtin_amdgcn_mfma_f32_16x16x32_bf16(aHi[mi], bA[ni], acc[4 + mi][ni], 0, 0, 0);
#pragma unroll
      for (int mi = 0; mi < 4; ++mi) aHi[mi] = A_FRAG(bs, 4 + ks, rowA + 64 + mi * 16);
#pragma unroll
      for (int mi = 0; mi < 4; ++mi)
#pragma unroll
        for (int ni = 0; ni < 4; ++ni)
          acc[mi][ni] = __builtin_amdgcn_mfma_f32_16x16x32_bf16(aLo[mi], bB[ni], acc[mi][ni], 0, 0, 0);
      asm volatile("s_waitcnt vmcnt(4)" ::: "memory");   // next tile A0B0 landed
      __builtin_amdgcn_s_barrier();

      // SEG C': read NEXT TILE's s0 frags from buf0; final MFMA of current tile
#pragma unroll
      for (int mi = 0; mi < 4; ++mi) aLo[mi] = A_FRAG(nb, ks, rowA + mi * 16);
#pragma unroll
      for (int ni = 0; ni < 4; ++ni) bA[ni] = B_FRAG(nb, ks, colB + ni * 16);
#pragma unroll
      for (int mi = 0; mi < 4; ++mi)
#pragma unroll
        for (int ni = 0; ni < 4; ++ni)
          acc[4 + mi][ni] = __builtin_amdgcn_mfma_f32_16x16x32_bf16(aHi[mi], bB[ni], acc[4 + mi][ni], 0, 0, 0);
    }

    // ---- epilogue for current tile (overlaps in-flight A1B1 staging of next tile)
    {
      const int col0 = n0 + wc * 64 + (lane & 15);
      const int row0 = m0 + wr * 128 + ((lane >> 4) << 2);
#pragma unroll
      for (int ni = 0; ni < 4; ++ni) {
        float bv = bias[col0 + ni * 16];
#pragma unroll
        for (int mi = 0; mi < 8; ++mi) {
#pragma unroll
          for (int rr = 0; rr < 4; ++rr) {
            __builtin_nontemporal_store(acc[mi][ni][rr] + bv,
                &C[(size_t)(row0 + mi * 16 + rr) * N_DIM + col0 + ni * 16]);
          }
        }
      }
    }
    if (last) break;

    // reset acc, rotate to next tile
#pragma unroll
    for (int i = 0; i < 8; ++i)
#pragma unroll
      for (int j = 0; j < 4; ++j) acc[i][j] = (f32x4){0.f, 0.f, 0.f, 0.f};
    m0 = m0n;
    n0 = n0n;
    tile = nextTile;
  }
#undef A_FRAG
#undef B_FRAG

  asm volatile("s_waitcnt vmcnt(0)" ::: "memory");  // no in-flight LDS writes at exit
}

// ---------------- fallback: fused-dequant fp32 tiled GEMM (no workspace) ----------------
__global__ __launch_bounds__(256) void gemm_fb(const float* __restrict__ A,
                                               const int* __restrict__ qweight,
                                               const int* __restrict__ qzeros,
                                               const float* __restrict__ scales,
                                               const float* __restrict__ bias,
                                               float* __restrict__ C) {
  __shared__ float as[64][17];
  __shared__ float bs2[16][65];
  int tid = threadIdx.x;
  int tx = tid & 15, ty = tid >> 4;
  int bn = blockIdx.x % (N_DIM / 64);
  int bm = blockIdx.x / (N_DIM / 64);
  int m0 = bm * 64, n0 = bn * 64;
  float acc[4][4] = {};
  for (int k0 = 0; k0 < K_DIM; k0 += 16) {
#pragma unroll
    for (int i = 0; i < 4; ++i) {
      int idx = i * 256 + tid;
      int r = idx >> 4, c = idx & 15;
      as[r][c] = A[(size_t)(m0 + r) * K_DIM + k0 + c];
    }
#pragma unroll
    for (int i = 0; i < 4; ++i) {
      int idx = i * 256 + tid;
      int r = idx >> 6, c = idx & 63;
      int k = k0 + r, n = n0 + c;
      int g = k >> 7, p = n >> 3, j = n & 7;
      int sh = ((j >> 1) << 2) | ((j & 1) << 4);
      int q = qweight[(size_t)k * PQ + p];
      int zq = qzeros[(size_t)g * PQ + p];
      bs2[r][c] = (float)(((q >> sh) & 0xF) - ((zq >> sh) & 0xF)) * scales[(size_t)g * N_DIM + n];
    }
    __syncthreads();
#pragma unroll
    for (int kk = 0; kk < 16; ++kk) {
      float av[4], bv[4];
#pragma unroll
      for (int i = 0; i < 4; ++i) av[i] = as[ty * 4 + i][kk];
#pragma unroll
      for (int i = 0; i < 4; ++i) bv[i] = bs2[kk][tx * 4 + i];
#pragma unroll
      for (int i = 0; i < 4; ++i)
#pragma unroll
        for (int j2 = 0; j2 < 4; ++j2) acc[i][j2] += av[i] * bv[j2];
    }
    __syncthreads();
  }
#pragma unroll
  for (int i = 0; i < 4; ++i)
#pragma unroll
    for (int j2 = 0; j2 < 4; ++j2)
      C[(size_t)(m0 + ty * 4 + i) * N_DIM + n0 + tx * 4 + j2] =
          acc[i][j2] + bias[n0 + tx * 4 + j2];
}

extern "C" void kernel_launch(void* const* d_in, const int* in_sizes, int n_in,
                              void* d_out, int out_size, void* d_ws, size_t ws_size,
                              hipStream_t stream) {
  const float* inputs = (const float*)d_in[0];
  const int* qweight = (const int*)d_in[1];
  const int* qzeros = (const int*)d_in[2];
  const float* scales = (const float*)d_in[3];
  const float* bias = (const float*)d_in[4];
  float* out = (float*)d_out;

  const size_t a_bytes = (size_t)M_DIM * K_DIM * 2;  // 32 MB
  const size_t w_bytes = (size_t)K_DIM * N_DIM * 2;  // 86 MB

  if (ws_size >= a_bytes + w_bytes) {
    unsigned short* a_kp = (unsigned short*)d_ws;
    unsigned short* wg = (unsigned short*)((char*)d_ws + a_bytes);
    convert_a_t<<<(M_DIM / 8) * (K_DIM / 256), 256, 0, stream>>>(inputs, a_kp);
    dequant_w<<<((K_DIM / 8) * N_DIM) / 256, 256, 0, stream>>>(qweight, qzeros, scales, wg);
    (void)hipFuncSetAttribute((const void*)gemm256,
                              hipFuncAttributeMaxDynamicSharedMemorySize, 131072);
    gemm256<<<GRID, 512, 131072, stream>>>(a_kp, wg, bias, out);
  } else {
    gemm_fb<<<(M_DIM / 64) * (N_DIM / 64), 256, 0, stream>>>(inputs, qweight, qzeros, scales,
                                                             bias, out);
  }
}

// Round 11
// 338.634 us; speedup vs baseline: 1.0339x; 1.0339x over previous
//
#include <hip/hip_runtime.h>

#define M_DIM 4096
#define K_DIM 4096
#define N_DIM 11008
#define PQ (N_DIM / 8)   // 1376 packed columns
#define NTILES 688       // (4096/256) * (11008/256)
#define GRID 256

typedef short short8 __attribute__((ext_vector_type(8)));
typedef float f32x4 __attribute__((ext_vector_type(4)));
typedef __attribute__((address_space(3))) void lds_void;
typedef const __attribute__((address_space(1))) void g_void;

__device__ __forceinline__ unsigned short f2bf(float f) {
  unsigned int u = __float_as_uint(f);
  u += 0x7FFFu + ((u >> 16) & 1u);   // round-to-nearest-even
  return (unsigned short)(u >> 16);
}

// ---- A convert + transpose (coalesced): fp32 [M][K] -> bf16 K-packed Ag[K/8][M][8] ----
__global__ __launch_bounds__(256) void convert_a_t(const float* __restrict__ a,
                                                   unsigned short* __restrict__ ag) {
  __shared__ unsigned short t[8][33][8];   // [m][kb_local][8], padded
  const int tid = threadIdx.x;
  const int mt = blockIdx.x & 511;         // m-tile (m0 = mt*8)
  const int kt = blockIdx.x >> 9;          // k-tile (k0 = kt*256)
  const int m0 = mt * 8;
  const int k0 = kt * 256;
  {
    const int m = tid >> 5, j = tid & 31;
    const float4* src = (const float4*)(a + (size_t)(m0 + m) * K_DIM + k0 + j * 8);
    float4 v0 = src[0];
    float4 v1 = src[1];
    short8 o;
    o[0] = (short)f2bf(v0.x); o[1] = (short)f2bf(v0.y);
    o[2] = (short)f2bf(v0.z); o[3] = (short)f2bf(v0.w);
    o[4] = (short)f2bf(v1.x); o[5] = (short)f2bf(v1.y);
    o[6] = (short)f2bf(v1.z); o[7] = (short)f2bf(v1.w);
    *(short8*)&t[m][j][0] = o;
  }
  __syncthreads();
  {
    const int kb = tid >> 3, mm = tid & 7;
    short8 w = *(const short8*)&t[mm][kb][0];
    *(short8*)(ag + ((size_t)(kt * 32 + kb) * M_DIM + m0 + mm) * 8) = w;
  }
}

// ---- Dequant: qweight [K][P] int32 -> Wg [K/8][N][8] bf16 (K-packed) ----
__global__ __launch_bounds__(256) void dequant_w(const int* __restrict__ qweight,
                                                 const int* __restrict__ qzeros,
                                                 const float* __restrict__ scales,
                                                 unsigned short* __restrict__ wg) {
  int idx = blockIdx.x * 256 + threadIdx.x;
  int n = idx % N_DIM;
  int kb = idx / N_DIM;                 // 0..511
  int g = kb >> 4;
  int p = n >> 3;
  int j = n & 7;
  int sh = ((j >> 1) << 2) | ((j & 1) << 4);   // 4*AWQ_rev[j]
  float zp = (float)((qzeros[g * PQ + p] >> sh) & 0xF);
  float sc = scales[(size_t)g * N_DIM + n];
  short8 o;
#pragma unroll
  for (int e = 0; e < 8; ++e) {
    int q = qweight[(size_t)(kb * 8 + e) * PQ + p];
    float w = ((float)((q >> sh) & 0xF) - zp) * sc;
    o[e] = (short)f2bf(w);
  }
  *(short8*)(wg + ((size_t)kb * N_DIM + n) * 8) = o;
}

// ---------------- 256x256 8-wave pipelined bf16 MFMA GEMM (persistent) ----------------
#define BM 256
#define BN 256
#define BK 64
#define NT (K_DIM / BK)   // 64 K-tiles
// LDS: 2 bufs x (A 16384 + B 16384) shorts = 128 KiB
// buf layout: A [kslot 0..7][row 0..255][8] ; B at +16384 same shape.

__device__ __forceinline__ void stage_half(const unsigned short* __restrict__ g, int ld, int off0,
                                           int krow0, unsigned short* ldsbase, int tid, int wid) {
#pragma unroll
  for (int i = 0; i < 2; ++i) {
    int c = i * 512 + tid;             // chunk id within the 16KB half
    const unsigned short* src = g + ((size_t)(krow0 + (c >> 8)) * ld + off0 + (c & 255)) * 8;
    unsigned short* dst = ldsbase + (i * 512 + wid * 64) * 8;  // wave-uniform; lane adds 16B
    __builtin_amdgcn_global_load_lds((g_void*)src, (lds_void*)dst, 16, 0, 0);
  }
}

__global__ __launch_bounds__(512, 2) void gemm256(const unsigned short* __restrict__ Ag,
                                                  const unsigned short* __restrict__ Wg,
                                                  const float* __restrict__ bias,
                                                  float* __restrict__ C) {
  extern __shared__ __align__(16) unsigned short lds[];   // 65536 shorts = 128 KB
  const int tid = threadIdx.x;
  const int lane = tid & 63;
  const int wid = tid >> 6;      // 0..7
  const int wr = wid >> 2;       // 0..1  (row half: 128 rows)
  const int wc = wid & 3;        // 0..3  (col quarter: 64 cols)

  const int ks = lane >> 4;           // k-slot within half (0..3)
  const int rowA = wr * 128 + (lane & 15);
  const int colB = wc * 64 + (lane & 15);

  // first tile for this block (XCD-bijective swizzle on tile index; 688 % 8 == 0)
  int tile = blockIdx.x;
  int wg0 = (tile & 7) * 86 + (tile >> 3);
  int m0 = (wg0 & 15) * BM;
  int n0 = (wg0 >> 4) * BN;

  f32x4 acc[8][4];
#pragma unroll
  for (int i = 0; i < 8; ++i)
#pragma unroll
    for (int j = 0; j < 4; ++j) acc[i][j] = (f32x4){0.f, 0.f, 0.f, 0.f};

#define A_FRAG(buf, kb, r) (*(const short8*)(lds + (buf) * 32768 + (kb) * 2048 + (r) * 8))
#define B_FRAG(buf, kb, c) (*(const short8*)(lds + (buf) * 32768 + 16384 + (kb) * 2048 + (c) * 8))

  short8 aLo[4], aHi[4], bA[4], bB[4];

  // ---- block prologue: stage tile0 fully; wait; read its s0 frags
  stage_half(Ag, M_DIM, m0, 0, lds + 0, tid, wid);              // A0
  stage_half(Wg, N_DIM, n0, 0, lds + 16384, tid, wid);          // B0
  stage_half(Ag, M_DIM, m0, 4, lds + 8192, tid, wid);           // A1
  stage_half(Wg, N_DIM, n0, 4, lds + 16384 + 8192, tid, wid);   // B1
  asm volatile("s_waitcnt vmcnt(0)" ::: "memory");
  __builtin_amdgcn_s_barrier();
#pragma unroll
  for (int mi = 0; mi < 4; ++mi) aLo[mi] = A_FRAG(0, ks, rowA + mi * 16);
#pragma unroll
  for (int ni = 0; ni < 4; ++ni) bA[ni] = B_FRAG(0, ks, colB + ni * 16);

  while (true) {
    const int nextTile = tile + GRID;
    const bool last = (nextTile >= NTILES);
    const int nI = last ? tile : nextTile;          // dummy-stage own tile at the end
    const int wgn = (nI & 7) * 86 + (nI >> 3);
    const int m0n = (wgn & 15) * BM;
    const int n0n = (wgn >> 4) * BN;

    // ================= main K loop (t = 0 .. NT-2), stages tile-local t+1 =================
    for (int t = 0; t < NT - 1; ++t) {
      const int bs = t & 1;
      const int nb = bs ^ 1;
      unsigned short* nA = lds + nb * 32768;
      unsigned short* nB = nA + 16384;

      // ===== SEG A: stage A0B0(t+1); read aHi(k0); MFMA P1; drain A1B1(t)
      stage_half(Ag, M_DIM, m0, (t + 1) * 8, nA, tid, wid);
      stage_half(Wg, N_DIM, n0, (t + 1) * 8, nB, tid, wid);
#pragma unroll
      for (int mi = 0; mi < 4; ++mi) aHi[mi] = A_FRAG(bs, ks, rowA + 64 + mi * 16);
#pragma unroll
      for (int mi = 0; mi < 4; ++mi)
#pragma unroll
        for (int ni = 0; ni < 4; ++ni)
          acc[mi][ni] = __builtin_amdgcn_mfma_f32_16x16x32_bf16(aLo[mi], bA[ni], acc[mi][ni], 0, 0, 0);
      asm volatile("s_waitcnt vmcnt(4)" ::: "memory");   // A1B1(t) landed
      __builtin_amdgcn_s_barrier();

      // ===== SEG B: MFMA P2; read s3 operands; stage A1B1(t+1); MFMA P3; drain A0B0(t+1)
#pragma unroll
      for (int mi = 0; mi < 4; ++mi) aLo[mi] = A_FRAG(bs, 4 + ks, rowA + mi * 16);
#pragma unroll
      for (int ni = 0; ni < 4; ++ni) bB[ni] = B_FRAG(bs, 4 + ks, colB + ni * 16);
#pragma unroll
      for (int mi = 0; mi < 4; ++mi)
#pragma unroll
        for (int ni = 0; ni < 4; ++ni)
          acc[4 + mi][ni] = __builtin_amdgcn_mfma_f32_16x16x32_bf16(aHi[mi], bA[ni], acc[4 + mi][ni], 0, 0, 0);
      stage_half(Ag, M_DIM, m0, (t + 1) * 8 + 4, nA + 8192, tid, wid);
      stage_half(Wg, N_DIM, n0, (t + 1) * 8 + 4, nB + 8192, tid, wid);
#pragma unroll
      for (int mi = 0; mi < 4; ++mi) aHi[mi] = A_FRAG(bs, 4 + ks, rowA + 64 + mi * 16);
#pragma unroll
      for (int mi = 0; mi < 4; ++mi)
#pragma unroll
        for (int ni = 0; ni < 4; ++ni)
          acc[mi][ni] = __builtin_amdgcn_mfma_f32_16x16x32_bf16(aLo[mi], bB[ni], acc[mi][ni], 0, 0, 0);
      asm volatile("s_waitcnt vmcnt(4)" ::: "memory");   // A0B0(t+1) landed
      __builtin_amdgcn_s_barrier();

      // ===== SEG C: read next-iter s0 frags from nb; MFMA P4
#pragma unroll
      for (int mi = 0; mi < 4; ++mi) aLo[mi] = A_FRAG(nb, ks, rowA + mi * 16);
#pragma unroll
      for (int ni = 0; ni < 4; ++ni) bA[ni] = B_FRAG(nb, ks, colB + ni * 16);
#pragma unroll
      for (int mi = 0; mi < 4; ++mi)
#pragma unroll
        for (int ni = 0; ni < 4; ++ni)
          acc[4 + mi][ni] = __builtin_amdgcn_mfma_f32_16x16x32_bf16(aHi[mi], bB[ni], acc[4 + mi][ni], 0, 0, 0);
    }

    // ================= peeled t = NT-1: stages NEXT TILE's halves into buf0 =================
    {
      const int bs = 1, nb = 0;   // (NT-1)&1 = 1
      unsigned short* nA = lds + nb * 32768;
      unsigned short* nB = nA + 16384;

      // SEG A': stage next tile A0B0
      stage_half(Ag, M_DIM, m0n, 0, nA, tid, wid);
      stage_half(Wg, N_DIM, n0n, 0, nB, tid, wid);
#pragma unroll
      for (int mi = 0; mi < 4; ++mi) aHi[mi] = A_FRAG(bs, ks, rowA + 64 + mi * 16);
#pragma unroll
      for (int mi = 0; mi < 4; ++mi)
#pragma unroll
        for (int ni = 0; ni < 4; ++ni)
          acc[mi][ni] = __builtin_amdgcn_mfma_f32_16x16x32_bf16(aLo[mi], bA[ni], acc[mi][ni], 0, 0, 0);
      asm volatile("s_waitcnt vmcnt(4)" ::: "memory");
      __builtin_amdgcn_s_barrier();

      // SEG B': stage next tile A1B1
#pragma unroll
      for (int mi = 0; mi < 4; ++mi) aLo[mi] = A_FRAG(bs, 4 + ks, rowA + mi * 16);
#pragma unroll
      for (int ni = 0; ni < 4; ++ni) bB[ni] = B_FRAG(bs, 4 + ks, colB + ni * 16);
#pragma unroll
      for (int mi = 0; mi < 4; ++mi)
#pragma unroll
        for (int ni = 0; ni < 4; ++ni)
          acc[4 + mi][ni] = __builtin_amdgcn_mfma_f32_16x16x32_bf16(aHi[mi], bA[ni], acc[4 + mi][ni], 0, 0, 0);
      stage_half(Ag, M_DIM, m0n, 4, nA + 8192, tid, wid);
      stage_half(Wg, N_DIM, n0n, 4, nB + 8192, tid, wid);
#pragma unroll
      for (int mi = 0; mi < 4; ++mi) aHi[mi] = A_FRAG(bs, 4 + ks, rowA + 64 + mi * 16);
#pragma unroll
      for (int mi = 0; mi < 4; ++mi)
#pragma unroll
        for (int ni = 0; ni < 4; ++ni)
          acc[mi][ni] = __builtin_amdgcn_mfma_f32_16x16x32_bf16(aLo[mi], bB[ni], acc[mi][ni], 0, 0, 0);
      asm volatile("s_waitcnt vmcnt(4)" ::: "memory");
      __builtin_amdgcn_s_barrier();

      // SEG C': read NEXT TILE's s0 frags from buf0; final MFMA of current tile
#pragma unroll
      for (int mi = 0; mi < 4; ++mi) aLo[mi] = A_FRAG(nb, ks, rowA + mi * 16);
#pragma unroll
      for (int ni = 0; ni < 4; ++ni) bA[ni] = B_FRAG(nb, ks, colB + ni * 16);
#pragma unroll
      for (int mi = 0; mi < 4; ++mi)
#pragma unroll
        for (int ni = 0; ni < 4; ++ni)
          acc[4 + mi][ni] = __builtin_amdgcn_mfma_f32_16x16x32_bf16(aHi[mi], bB[ni], acc[4 + mi][ni], 0, 0, 0);
    }

    // ---- epilogue for current tile (overlaps in-flight A1B1 staging of next tile)
    {
      const int col0 = n0 + wc * 64 + (lane & 15);
      const int row0 = m0 + wr * 128 + ((lane >> 4) << 2);
#pragma unroll
      for (int ni = 0; ni < 4; ++ni) {
        float bv = bias[col0 + ni * 16];
#pragma unroll
        for (int mi = 0; mi < 8; ++mi) {
#pragma unroll
          for (int rr = 0; rr < 4; ++rr) {
            __builtin_nontemporal_store(acc[mi][ni][rr] + bv,
                &C[(size_t)(row0 + mi * 16 + rr) * N_DIM + col0 + ni * 16]);
          }
        }
      }
    }
    if (last) break;

    // reset acc, rotate to next tile
#pragma unroll
    for (int i = 0; i < 8; ++i)
#pragma unroll
      for (int j = 0; j < 4; ++j) acc[i][j] = (f32x4){0.f, 0.f, 0.f, 0.f};
    m0 = m0n;
    n0 = n0n;
    tile = nextTile;
  }
#undef A_FRAG
#undef B_FRAG

  asm volatile("s_waitcnt vmcnt(0)" ::: "memory");  // no in-flight LDS writes at exit
}

// ---------------- fallback: fused-dequant fp32 tiled GEMM (no workspace) ----------------
__global__ __launch_bounds__(256) void gemm_fb(const float* __restrict__ A,
                                               const int* __restrict__ qweight,
                                               const int* __restrict__ qzeros,
                                               const float* __restrict__ scales,
                                               const float* __restrict__ bias,
                                               float* __restrict__ C) {
  __shared__ float as[64][17];
  __shared__ float bs2[16][65];
  int tid = threadIdx.x;
  int tx = tid & 15, ty = tid >> 4;
  int bn = blockIdx.x % (N_DIM / 64);
  int bm = blockIdx.x / (N_DIM / 64);
  int m0 = bm * 64, n0 = bn * 64;
  float acc[4][4] = {};
  for (int k0 = 0; k0 < K_DIM; k0 += 16) {
#pragma unroll
    for (int i = 0; i < 4; ++i) {
      int idx = i * 256 + tid;
      int r = idx >> 4, c = idx & 15;
      as[r][c] = A[(size_t)(m0 + r) * K_DIM + k0 + c];
    }
#pragma unroll
    for (int i = 0; i < 4; ++i) {
      int idx = i * 256 + tid;
      int r = idx >> 6, c = idx & 63;
      int k = k0 + r, n = n0 + c;
      int g = k >> 7, p = n >> 3, j = n & 7;
      int sh = ((j >> 1) << 2) | ((j & 1) << 4);
      int q = qweight[(size_t)k * PQ + p];
      int zq = qzeros[(size_t)g * PQ + p];
      bs2[r][c] = (float)(((q >> sh) & 0xF) - ((zq >> sh) & 0xF)) * scales[(size_t)g * N_DIM + n];
    }
    __syncthreads();
#pragma unroll
    for (int kk = 0; kk < 16; ++kk) {
      float av[4], bv[4];
#pragma unroll
      for (int i = 0; i < 4; ++i) av[i] = as[ty * 4 + i][kk];
#pragma unroll
      for (int i = 0; i < 4; ++i) bv[i] = bs2[kk][tx * 4 + i];
#pragma unroll
      for (int i = 0; i < 4; ++i)
#pragma unroll
        for (int j2 = 0; j2 < 4; ++j2) acc[i][j2] += av[i] * bv[j2];
    }
    __syncthreads();
  }
#pragma unroll
  for (int i = 0; i < 4; ++i)
#pragma unroll
    for (int j2 = 0; j2 < 4; ++j2)
      C[(size_t)(m0 + ty * 4 + i) * N_DIM + n0 + tx * 4 + j2] =
          acc[i][j2] + bias[n0 + tx * 4 + j2];
}

extern "C" void kernel_launch(void* const* d_in, const int* in_sizes, int n_in,
                              void* d_out, int out_size, void* d_ws, size_t ws_size,
                              hipStream_t stream) {
  const float* inputs = (const float*)d_in[0];
  const int* qweight = (const int*)d_in[1];
  const int* qzeros = (const int*)d_in[2];
  const float* scales = (const float*)d_in[3];
  const float* bias = (const float*)d_in[4];
  float* out = (float*)d_out;

  const size_t a_bytes = (size_t)M_DIM * K_DIM * 2;  // 32 MB
  const size_t w_bytes = (size_t)K_DIM * N_DIM * 2;  // 86 MB

  if (ws_size >= a_bytes + w_bytes) {
    unsigned short* a_kp = (unsigned short*)d_ws;
    unsigned short* wg = (unsigned short*)((char*)d_ws + a_bytes);
    convert_a_t<<<(M_DIM / 8) * (K_DIM / 256), 256, 0, stream>>>(inputs, a_kp);
    dequant_w<<<((K_DIM / 8) * N_DIM) / 256, 256, 0, stream>>>(qweight, qzeros, scales, wg);
    (void)hipFuncSetAttribute((const void*)gemm256,
                              hipFuncAttributeMaxDynamicSharedMemorySize, 131072);
    gemm256<<<GRID, 512, 131072, stream>>>(a_kp, wg, bias, out);
  } else {
    gemm_fb<<<(M_DIM / 64) * (N_DIM / 64), 256, 0, stream>>>(inputs, qweight, qzeros, scales,
                                                             bias, out);
  }
}